// Round 12
// baseline (60.065 us; speedup 1.0000x reference)
//
#include <hip/hip_runtime.h>
#include <hip/hip_bf16.h>

#define NEG 0.2f
#define LOG2E 1.4426950408889634f

typedef __attribute__((ext_vector_type(8))) short bf16x8;
typedef __attribute__((ext_vector_type(4))) float f32x4;
typedef __attribute__((ext_vector_type(16))) float f32x16;
typedef __attribute__((ext_vector_type(4))) int int4v;

__device__ __forceinline__ float lrelu(float t){ return fmaxf(t, NEG * t); }
__device__ __forceinline__ float fast_exp2(float x){
  float r; asm("v_exp_f32 %0, %1" : "=v"(r) : "v"(x)); return r;
}
__device__ __forceinline__ unsigned short f2bf(float f){   // RNE
  union { float f; unsigned int u; } v; v.f = f;
  unsigned int r = v.u + 0x7FFFu + ((v.u >> 16) & 1u);
  return (unsigned short)(r >> 16);
}
// order-preserving float->uint mapping for atomicMax
__device__ __forceinline__ unsigned fmap(float f){
  unsigned u = __float_as_uint(f);
  return (u & 0x80000000u) ? ~u : (u | 0x80000000u);
}
__device__ __forceinline__ float funmap(unsigned u){
  return (u & 0x80000000u) ? __uint_as_float(u & 0x7FFFFFFFu) : __uint_as_float(~u);
}

// ---------------- K0: Wt[o][k] = bf16(W[k][o]), 16 blocks (8 o-rows each) ----------------
__global__ __launch_bounds__(256) void k0_wt(const float* __restrict__ W,
                                             unsigned short* __restrict__ Wt){
  __shared__ __align__(16) unsigned short wl[8*136];
  const int t = threadIdx.x;
  const int p = blockIdx.x;            // o-slab [p*8, p*8+8)
  {
    const int k = t >> 1, h = t & 1;   // read W[k][p*8 + h*4 .. +3]
    f32x4 v = *(const f32x4*)(W + k*128 + p*8 + h*4);
#pragma unroll
    for (int e = 0; e < 4; ++e) wl[(h*4 + e)*136 + k] = f2bf(v[e]);
  }
  __syncthreads();
  {
    const int ol = t >> 5, ks = (t & 31) * 4;
    unsigned int lo = *(const unsigned int*)(wl + ol*136 + ks);
    unsigned int hi = *(const unsigned int*)(wl + ol*136 + ks + 2);
    *(unsigned int*)(Wt + (p*8 + ol)*128 + ks)     = lo;
    *(unsigned int*)(Wt + (p*8 + ol)*128 + ks + 2) = hi;
  }
}

// ---------------- K1: h^T via MFMA + scaled s_src/s_dst (+batch-max atomic) + ht store ----------------
__global__ __launch_bounds__(256) void k1_fused(const float* __restrict__ x,
                                                const unsigned short* __restrict__ Wt,
                                                const float* __restrict__ a,
                                                unsigned short* __restrict__ ht,
                                                float* __restrict__ ssrcL,
                                                float* __restrict__ sdstL,
                                                unsigned* __restrict__ Mu){
  __shared__ __align__(16) unsigned short wtl[128*136];
  __shared__ __align__(16) unsigned short xl[32*136];
  __shared__ __align__(16) unsigned short tlw[128*34];
  __shared__ float sred[2][4][2][16];
  const int t = threadIdx.x;
  const int bx = blockIdx.x;                 // b*64 + jt
  const int b  = bx >> 6;
  const int jt = bx & 63;
  const long rowbase = (long)bx * 32;
  {
    const int o = t >> 1, seg = (t & 1) * 64;
    const int4v* src = (const int4v*)(Wt + o*128 + seg);
    int4v* dst = (int4v*)(wtl + o*136 + seg);
#pragma unroll
    for (int g = 0; g < 8; ++g) dst[g] = src[g];
  }
  {
    const int i = t >> 3, ks = (t & 7) * 16;
    const f32x4* src = (const f32x4*)(x + (rowbase + i)*128 + ks);
    unsigned int q[8];
#pragma unroll
    for (int g = 0; g < 4; ++g){
      f32x4 v = src[g];
      q[g*2]   = (unsigned)f2bf(v[0]) | ((unsigned)f2bf(v[1]) << 16);
      q[g*2+1] = (unsigned)f2bf(v[2]) | ((unsigned)f2bf(v[3]) << 16);
    }
    int4v* dst = (int4v*)(xl + i*136 + ks);
    dst[0] = *(int4v*)&q[0];
    dst[1] = *(int4v*)&q[4];
  }
  __syncthreads();
  const int w = t >> 6, lane = t & 63, lr = lane & 15, hi = lane >> 4;
  f32x4 zro = {0.f, 0.f, 0.f, 0.f};
  f32x4 acc00 = zro, acc01 = zro, acc10 = zro, acc11 = zro;
#pragma unroll
  for (int ks = 0; ks < 4; ++ks){
    const bf16x8 a0 = *(const bf16x8*)(wtl + (w*32      + lr)*136 + ks*32 + hi*8);
    const bf16x8 a1 = *(const bf16x8*)(wtl + (w*32 + 16 + lr)*136 + ks*32 + hi*8);
    const bf16x8 b0 = *(const bf16x8*)(xl + (     lr)*136 + ks*32 + hi*8);
    const bf16x8 b1 = *(const bf16x8*)(xl + (16 + lr)*136 + ks*32 + hi*8);
    acc00 = __builtin_amdgcn_mfma_f32_16x16x32_bf16(a0, b0, acc00, 0, 0, 0);
    acc01 = __builtin_amdgcn_mfma_f32_16x16x32_bf16(a0, b1, acc01, 0, 0, 0);
    acc10 = __builtin_amdgcn_mfma_f32_16x16x32_bf16(a1, b0, acc10, 0, 0, 0);
    acc11 = __builtin_amdgcn_mfma_f32_16x16x32_bf16(a1, b1, acc11, 0, 0, 0);
  }
  {
    const f32x4 as0 = *(const f32x4*)(a +       w*32      + hi*4);
    const f32x4 as1 = *(const f32x4*)(a +       w*32 + 16 + hi*4);
    const f32x4 ad0 = *(const f32x4*)(a + 128 + w*32      + hi*4);
    const f32x4 ad1 = *(const f32x4*)(a + 128 + w*32 + 16 + hi*4);
    float ps0, ps1, pd0, pd1;
    {
      f32x4 u = acc00*as0 + acc10*as1;  ps0 = u[0]+u[1]+u[2]+u[3];
      f32x4 v = acc01*as0 + acc11*as1;  ps1 = v[0]+v[1]+v[2]+v[3];
      f32x4 p = acc00*ad0 + acc10*ad1;  pd0 = p[0]+p[1]+p[2]+p[3];
      f32x4 r = acc01*ad0 + acc11*ad1;  pd1 = r[0]+r[1]+r[2]+r[3];
    }
#pragma unroll
    for (int off = 16; off <= 32; off <<= 1){
      ps0 += __shfl_xor(ps0, off); ps1 += __shfl_xor(ps1, off);
      pd0 += __shfl_xor(pd0, off); pd1 += __shfl_xor(pd1, off);
    }
    if (hi == 0){
      sred[0][w][0][lr] = ps0; sred[0][w][1][lr] = ps1;
      sred[1][w][0][lr] = pd0; sred[1][w][1][lr] = pd1;
    }
  }
#pragma unroll
  for (int q = 0; q < 4; ++q){
    tlw[(w*32      + hi*4 + q)*34      + lr] = f2bf(acc00[q]);
    tlw[(w*32      + hi*4 + q)*34 + 16 + lr] = f2bf(acc01[q]);
    tlw[(w*32 + 16 + hi*4 + q)*34      + lr] = f2bf(acc10[q]);
    tlw[(w*32 + 16 + hi*4 + q)*34 + 16 + lr] = f2bf(acc11[q]);
  }
  __syncthreads();
  {
    const int o = t >> 1, jseg = (t & 1) * 16;
    const unsigned int* src = (const unsigned int*)(tlw + o*34 + jseg);
    unsigned int p[8];
#pragma unroll
    for (int g = 0; g < 8; ++g) p[g] = src[g];
    unsigned short* dst = ht + (long)b*262144 + (long)o*2048 + jt*32 + jseg;
    ((int4v*)dst)[0] = *(int4v*)&p[0];
    ((int4v*)dst)[1] = *(int4v*)&p[4];
  }
  if (t < 64){
    const int sel = t >> 5, jl = t & 31;
    const int ig = jl >> 4, l2 = jl & 15;
    const float s = (sred[sel][0][ig][l2] + sred[sel][1][ig][l2]
                   + sred[sel][2][ig][l2] + sred[sel][3][ig][l2]) * LOG2E;
    if (sel == 0){
      ssrcL[rowbase + jl] = s;
    } else {
      sdstL[rowbase + jl] = s;
      unsigned u = fmap(s);
#pragma unroll
      for (int off = 1; off <= 16; off <<= 1){
        unsigned o2 = (unsigned)__shfl_xor((int)u, off);
        u = u > o2 ? u : o2;
      }
      if (jl == 0) atomicMax(&Mu[b], u);
    }
  }
}

// ---------------- K2: per-row C_i = m_L + log2(sum_j 2^(lrelu(siL+sjL)-m_L)) ----------------
__global__ __launch_bounds__(256) void k2_ml(const float* __restrict__ ssrcL,
                                             const float* __restrict__ sdstL,
                                             const unsigned* __restrict__ Mu,
                                             float* __restrict__ carr){
  const int lane = threadIdx.x & 63;
  const long row = (long)blockIdx.x * 4 + (threadIdx.x >> 6);
  const int b = (int)(row >> 11);
  const float siL = ssrcL[row];
  const float mL = lrelu(siL + funmap(Mu[b]));
  const float* sd = sdstL + (long)b*2048;
  float sum = 0.f;
#pragma unroll
  for (int k = 0; k < 8; ++k){
    f32x4 v = *(const f32x4*)(sd + lane*4 + k*256);
#pragma unroll
    for (int e = 0; e < 4; ++e) sum += fast_exp2(lrelu(siL + v[e]) - mL);
  }
#pragma unroll
  for (int off = 1; off <= 32; off <<= 1) sum += __shfl_xor(sum, off);
  if (lane == 0) carr[row] = mL + __log2f(sum);
}

// ---------------- K3: out = LR( (adj + alpha) @ h ), cooperative-weight MFMA (r7 verbatim) ----------------
__global__ __launch_bounds__(256, 2) void k3_main(const float* __restrict__ adj,
                                                  const unsigned short* __restrict__ ht,
                                                  const float* __restrict__ ssrcL,
                                                  const float* __restrict__ sdstL,
                                                  const float* __restrict__ carr,
                                                  float* __restrict__ out){
  __shared__ __align__(16) unsigned short httile[2][128][64];  // 32 KB (o-rows x j)
  __shared__ __align__(16) unsigned short wtile[2][32][64];    // 8 KB  (i-rows x j)
  const int t    = threadIdx.x;
  const int bxr  = blockIdx.x;
  const int bx   = ((bxr & 7) << 6) | (bxr >> 3);   // batch -> one XCD
  const int b    = bx >> 6;
  const int i0   = (bx & 63) * 32;
  const int w    = t >> 6, lane = t & 63;
  const int r32  = lane & 31, hl = lane >> 5;
  const int r7   = r32 & 7;
  const int wchunk = (w*2 + hl) ^ r7;               // wtile write position
  const long rowg = (long)b*2048 + i0 + r32;
  const float siL = ssrcL[rowg];
  const float Ci  = carr[rowg];
  const float* adjL = adj + rowg*2048 + w*16 + hl*8;      // this lane's weight slice
  const float* sdbL = sdstL + (long)b*2048 + w*16 + hl*8;
  // staging source (this wave's 32 o-rows, source pre-swizzled by j-chunk):
  const unsigned short* sgbase = ht + (long)b*262144
                               + (long)(w*32 + (lane >> 3))*2048
                               + ((lane & 7) ^ (lane >> 3)) * 8;

  f32x16 acc;
#pragma unroll
  for (int e = 0; e < 16; ++e) acc[e] = 0.f;
  f32x4 aA0, aA1, dA0, dA1, aB0, aB1, dB0, dB1;

  // ---- prologue: stage tile0 -> buf0; adj/sd sets for steps 0,1 ----
#pragma unroll
  for (int it = 0; it < 4; ++it)
    __builtin_amdgcn_global_load_lds(
      (const __attribute__((address_space(1))) void*)(sgbase + it*16384),
      (__attribute__((address_space(3))) void*)&httile[0][w*32 + it*8][0], 16, 0, 0);
  aA0 = *(const f32x4*)(adjL);      aA1 = *(const f32x4*)(adjL + 4);
  dA0 = *(const f32x4*)(sdbL);      dA1 = *(const f32x4*)(sdbL + 4);
  aB0 = *(const f32x4*)(adjL + 64); aB1 = *(const f32x4*)(adjL + 68);
  dB0 = *(const f32x4*)(sdbL + 64); dB1 = *(const f32x4*)(sdbL + 68);

#define K3_STEP(JB, BUF, DO_STAGE, DO_REFILL, VMSTR, AV0, AV1, DV0, DV1) do{     \
    if (DO_STAGE){                                                               \
      _Pragma("unroll")                                                          \
      for (int it = 0; it < 4; ++it)                                             \
        __builtin_amdgcn_global_load_lds(                                        \
          (const __attribute__((address_space(1))) void*)(sgbase + (JB) + 64 + it*16384), \
          (__attribute__((address_space(3))) void*)&httile[(BUF)^1][w*32 + it*8][0], 16, 0, 0); \
    }                                                                            \
    {  float wv[8];                                                              \
       _Pragma("unroll")                                                         \
       for (int e = 0; e < 4; ++e){                                              \
         wv[e]   = AV0[e] + fast_exp2(lrelu(siL + DV0[e]) - Ci);                 \
         wv[4+e] = AV1[e] + fast_exp2(lrelu(siL + DV1[e]) - Ci);                 \
       }                                                                         \
       const unsigned p01 = __builtin_amdgcn_perm(__float_as_uint(wv[1]), __float_as_uint(wv[0]), 0x07060302u); \
       const unsigned p23 = __builtin_amdgcn_perm(__float_as_uint(wv[3]), __float_as_uint(wv[2]), 0x07060302u); \
       const unsigned p45 = __builtin_amdgcn_perm(__float_as_uint(wv[5]), __float_as_uint(wv[4]), 0x07060302u); \
       const unsigned p67 = __builtin_amdgcn_perm(__float_as_uint(wv[7]), __float_as_uint(wv[6]), 0x07060302u); \
       int4v ai = {(int)p01, (int)p23, (int)p45, (int)p67};                      \
       *(int4v*)&wtile[BUF][r32][wchunk*8] = ai;                                 \
    }                                                                            \
    if (DO_REFILL){                                                              \
      AV0 = *(const f32x4*)(adjL + (JB) + 128);                                  \
      AV1 = *(const f32x4*)(adjL + (JB) + 132);                                  \
      DV0 = *(const f32x4*)(sdbL + (JB) + 128);                                  \
      DV1 = *(const f32x4*)(sdbL + (JB) + 132);                                  \
    }                                                                            \
    asm volatile("s_waitcnt vmcnt(" VMSTR ") lgkmcnt(0)" ::: "memory");          \
    __builtin_amdgcn_sched_barrier(0);                                           \
    __builtin_amdgcn_s_barrier();                                                \
    __builtin_amdgcn_sched_barrier(0);                                           \
    __builtin_amdgcn_s_setprio(1);                                               \
    _Pragma("unroll")                                                            \
    for (int g = 0; g < 4; ++g){                                                 \
      const int pos = ((2*g + hl) ^ r7) * 8;                                     \
      const bf16x8 afr = *(const bf16x8*)&wtile[BUF][r32][pos];                  \
      const bf16x8 bfr = *(const bf16x8*)&httile[BUF][w*32 + r32][pos];          \
      acc = __builtin_amdgcn_mfma_f32_32x32x16_bf16(afr, bfr, acc, 0, 0, 0);     \
    }                                                                            \
    __builtin_amdgcn_s_setprio(0);                                               \
    __builtin_amdgcn_sched_barrier(0);                                           \
  }while(0)

  for (int kt = 0; kt < 30; kt += 2){
    const int jb0 = kt * 64;
    K3_STEP(jb0,      0, 1, 1, "8", aA0, aA1, dA0, dA1);
    K3_STEP(jb0 + 64, 1, 1, 1, "8", aB0, aB1, dB0, dB1);
  }
  K3_STEP(1920, 0, 1, 0, "8", aA0, aA1, dA0, dA1);  // s=30: stage tile 31
  K3_STEP(1984, 1, 0, 0, "0", aB0, aB1, dB0, dB1);  // s=31: final
#undef K3_STEP

  // ---- epilogue: direct store (full-K acc per wave) ----
#pragma unroll
  for (int rg = 0; rg < 16; ++rg){
    const int rr = (rg & 3) + 8*(rg >> 2) + 4*hl;
    out[((long)b*2048 + i0 + rr)*128 + w*32 + r32] = lrelu(acc[rg]);
  }
}

extern "C" void kernel_launch(void* const* d_in, const int* in_sizes, int n_in,
                              void* d_out, int out_size, void* d_ws, size_t ws_size,
                              hipStream_t stream){
  const float* x   = (const float*)d_in[0];
  const float* adj = (const float*)d_in[1];
  const float* W   = (const float*)d_in[2];
  const float* a   = (const float*)d_in[3];
  float* out = (float*)d_out;
  char* ws = (char*)d_ws;

  unsigned short* ht    = (unsigned short*)(ws);              // 4 MB
  float*          ssrcL = (float*)(ws + 4194304);             // 64 KB
  float*          sdstL = (float*)(ws + 4259840);             // 64 KB
  float*          carr  = (float*)(ws + 4325376);             // 64 KB
  unsigned short* Wt    = (unsigned short*)(ws + 4390912);    // 32 KB
  unsigned*       Mu    = (unsigned*)(ws + 4423680);          // 32 B

  hipMemsetAsync(Mu, 0, 32, stream);
  k0_wt   <<<16,   256, 0, stream>>>(W, Wt);
  k1_fused<<<512,  256, 0, stream>>>(x, Wt, a, ht, ssrcL, sdstL, Mu);
  k2_ml   <<<4096, 256, 0, stream>>>(ssrcL, sdstL, Mu, carr);
  k3_main <<<512,  256, 0, stream>>>(adj, ht, ssrcL, sdstL, carr, out);
}

// Round 13
// 57.390 us; speedup vs baseline: 1.0466x; 1.0466x over previous
//
#include <hip/hip_runtime.h>
#include <hip/hip_bf16.h>

#define NEG 0.2f
#define LOG2E 1.4426950408889634f

typedef __attribute__((ext_vector_type(8))) short bf16x8;
typedef __attribute__((ext_vector_type(4))) float f32x4;
typedef __attribute__((ext_vector_type(16))) float f32x16;
typedef __attribute__((ext_vector_type(4))) int int4v;

__device__ __forceinline__ float lrelu(float t){ return fmaxf(t, NEG * t); }
__device__ __forceinline__ float fast_exp2(float x){
  float r; asm("v_exp_f32 %0, %1" : "=v"(r) : "v"(x)); return r;
}
__device__ __forceinline__ unsigned short f2bf(float f){   // RNE
  union { float f; unsigned int u; } v; v.f = f;
  unsigned int r = v.u + 0x7FFFu + ((v.u >> 16) & 1u);
  return (unsigned short)(r >> 16);
}
// order-preserving float->uint mapping for atomicMax
__device__ __forceinline__ unsigned fmap(float f){
  unsigned u = __float_as_uint(f);
  return (u & 0x80000000u) ? ~u : (u | 0x80000000u);
}
__device__ __forceinline__ float funmap(unsigned u){
  return (u & 0x80000000u) ? __uint_as_float(u & 0x7FFFFFFFu) : __uint_as_float(~u);
}

// ---------------- K0: Wt[o][k] = bf16(W[k][o]), 16 blocks; block 0 zeroes Mu ----------------
__global__ __launch_bounds__(256) void k0_wt(const float* __restrict__ W,
                                             unsigned short* __restrict__ Wt,
                                             unsigned* __restrict__ Mu){
  __shared__ __align__(16) unsigned short wl[8*136];
  const int t = threadIdx.x;
  const int p = blockIdx.x;            // o-slab [p*8, p*8+8)
  if (p == 0 && t < 8) Mu[t] = 0u;     // init batch-max accumulators (replaces memset)
  {
    const int k = t >> 1, h = t & 1;   // read W[k][p*8 + h*4 .. +3]
    f32x4 v = *(const f32x4*)(W + k*128 + p*8 + h*4);
#pragma unroll
    for (int e = 0; e < 4; ++e) wl[(h*4 + e)*136 + k] = f2bf(v[e]);
  }
  __syncthreads();
  {
    const int ol = t >> 5, ks = (t & 31) * 4;
    unsigned int lo = *(const unsigned int*)(wl + ol*136 + ks);
    unsigned int hi = *(const unsigned int*)(wl + ol*136 + ks + 2);
    *(unsigned int*)(Wt + (p*8 + ol)*128 + ks)     = lo;
    *(unsigned int*)(Wt + (p*8 + ol)*128 + ks + 2) = hi;
  }
}

// ---------------- K1: h^T via MFMA + scaled s_src/s_dst (+batch-max atomic) + ht store ----------------
__global__ __launch_bounds__(256) void k1_fused(const float* __restrict__ x,
                                                const unsigned short* __restrict__ Wt,
                                                const float* __restrict__ a,
                                                unsigned short* __restrict__ ht,
                                                float* __restrict__ ssrcL,
                                                float* __restrict__ sdstL,
                                                unsigned* __restrict__ Mu){
  __shared__ __align__(16) unsigned short wtl[128*136];
  __shared__ __align__(16) unsigned short xl[32*136];
  __shared__ __align__(16) unsigned short tlw[128*34];
  __shared__ float sred[2][4][2][16];
  const int t = threadIdx.x;
  const int bx = blockIdx.x;                 // b*64 + jt
  const int b  = bx >> 6;
  const int jt = bx & 63;
  const long rowbase = (long)bx * 32;
  {
    const int o = t >> 1, seg = (t & 1) * 64;
    const int4v* src = (const int4v*)(Wt + o*128 + seg);
    int4v* dst = (int4v*)(wtl + o*136 + seg);
#pragma unroll
    for (int g = 0; g < 8; ++g) dst[g] = src[g];
  }
  {
    const int i = t >> 3, ks = (t & 7) * 16;
    const f32x4* src = (const f32x4*)(x + (rowbase + i)*128 + ks);
    unsigned int q[8];
#pragma unroll
    for (int g = 0; g < 4; ++g){
      f32x4 v = src[g];
      q[g*2]   = (unsigned)f2bf(v[0]) | ((unsigned)f2bf(v[1]) << 16);
      q[g*2+1] = (unsigned)f2bf(v[2]) | ((unsigned)f2bf(v[3]) << 16);
    }
    int4v* dst = (int4v*)(xl + i*136 + ks);
    dst[0] = *(int4v*)&q[0];
    dst[1] = *(int4v*)&q[4];
  }
  __syncthreads();
  const int w = t >> 6, lane = t & 63, lr = lane & 15, hi = lane >> 4;
  f32x4 zro = {0.f, 0.f, 0.f, 0.f};
  f32x4 acc00 = zro, acc01 = zro, acc10 = zro, acc11 = zro;
#pragma unroll
  for (int ks = 0; ks < 4; ++ks){
    const bf16x8 a0 = *(const bf16x8*)(wtl + (w*32      + lr)*136 + ks*32 + hi*8);
    const bf16x8 a1 = *(const bf16x8*)(wtl + (w*32 + 16 + lr)*136 + ks*32 + hi*8);
    const bf16x8 b0 = *(const bf16x8*)(xl + (     lr)*136 + ks*32 + hi*8);
    const bf16x8 b1 = *(const bf16x8*)(xl + (16 + lr)*136 + ks*32 + hi*8);
    acc00 = __builtin_amdgcn_mfma_f32_16x16x32_bf16(a0, b0, acc00, 0, 0, 0);
    acc01 = __builtin_amdgcn_mfma_f32_16x16x32_bf16(a0, b1, acc01, 0, 0, 0);
    acc10 = __builtin_amdgcn_mfma_f32_16x16x32_bf16(a1, b0, acc10, 0, 0, 0);
    acc11 = __builtin_amdgcn_mfma_f32_16x16x32_bf16(a1, b1, acc11, 0, 0, 0);
  }
  {
    const f32x4 as0 = *(const f32x4*)(a +       w*32      + hi*4);
    const f32x4 as1 = *(const f32x4*)(a +       w*32 + 16 + hi*4);
    const f32x4 ad0 = *(const f32x4*)(a + 128 + w*32      + hi*4);
    const f32x4 ad1 = *(const f32x4*)(a + 128 + w*32 + 16 + hi*4);
    float ps0, ps1, pd0, pd1;
    {
      f32x4 u = acc00*as0 + acc10*as1;  ps0 = u[0]+u[1]+u[2]+u[3];
      f32x4 v = acc01*as0 + acc11*as1;  ps1 = v[0]+v[1]+v[2]+v[3];
      f32x4 p = acc00*ad0 + acc10*ad1;  pd0 = p[0]+p[1]+p[2]+p[3];
      f32x4 r = acc01*ad0 + acc11*ad1;  pd1 = r[0]+r[1]+r[2]+r[3];
    }
#pragma unroll
    for (int off = 16; off <= 32; off <<= 1){
      ps0 += __shfl_xor(ps0, off); ps1 += __shfl_xor(ps1, off);
      pd0 += __shfl_xor(pd0, off); pd1 += __shfl_xor(pd1, off);
    }
    if (hi == 0){
      sred[0][w][0][lr] = ps0; sred[0][w][1][lr] = ps1;
      sred[1][w][0][lr] = pd0; sred[1][w][1][lr] = pd1;
    }
  }
#pragma unroll
  for (int q = 0; q < 4; ++q){
    tlw[(w*32      + hi*4 + q)*34      + lr] = f2bf(acc00[q]);
    tlw[(w*32      + hi*4 + q)*34 + 16 + lr] = f2bf(acc01[q]);
    tlw[(w*32 + 16 + hi*4 + q)*34      + lr] = f2bf(acc10[q]);
    tlw[(w*32 + 16 + hi*4 + q)*34 + 16 + lr] = f2bf(acc11[q]);
  }
  __syncthreads();
  {
    const int o = t >> 1, jseg = (t & 1) * 16;
    const unsigned int* src = (const unsigned int*)(tlw + o*34 + jseg);
    unsigned int p[8];
#pragma unroll
    for (int g = 0; g < 8; ++g) p[g] = src[g];
    unsigned short* dst = ht + (long)b*262144 + (long)o*2048 + jt*32 + jseg;
    ((int4v*)dst)[0] = *(int4v*)&p[0];
    ((int4v*)dst)[1] = *(int4v*)&p[4];
  }
  if (t < 64){
    const int sel = t >> 5, jl = t & 31;
    const int ig = jl >> 4, l2 = jl & 15;
    const float s = (sred[sel][0][ig][l2] + sred[sel][1][ig][l2]
                   + sred[sel][2][ig][l2] + sred[sel][3][ig][l2]) * LOG2E;
    if (sel == 0){
      ssrcL[rowbase + jl] = s;
    } else {
      sdstL[rowbase + jl] = s;
      unsigned u = fmap(s);
#pragma unroll
      for (int off = 1; off <= 16; off <<= 1){
        unsigned o2 = (unsigned)__shfl_xor((int)u, off);
        u = u > o2 ? u : o2;
      }
      if (jl == 0) atomicMax(&Mu[b], u);
    }
  }
}

// ---------------- K2: per-row C_i = m_L + log2(sum_j 2^(lrelu(siL+sjL)-m_L)) ----------------
__global__ __launch_bounds__(256) void k2_ml(const float* __restrict__ ssrcL,
                                             const float* __restrict__ sdstL,
                                             const unsigned* __restrict__ Mu,
                                             float* __restrict__ carr){
  const int lane = threadIdx.x & 63;
  const long row = (long)blockIdx.x * 4 + (threadIdx.x >> 6);
  const int b = (int)(row >> 11);
  const float siL = ssrcL[row];
  const float mL = lrelu(siL + funmap(Mu[b]));
  const float* sd = sdstL + (long)b*2048;
  float sum = 0.f;
#pragma unroll
  for (int k = 0; k < 8; ++k){
    f32x4 v = *(const f32x4*)(sd + lane*4 + k*256);
#pragma unroll
    for (int e = 0; e < 4; ++e) sum += fast_exp2(lrelu(siL + v[e]) - mL);
  }
#pragma unroll
  for (int off = 1; off <= 32; off <<= 1) sum += __shfl_xor(sum, off);
  if (lane == 0) carr[row] = mL + __log2f(sum);
}

// ---------------- K3: out = LR( (adj + alpha) @ h ), cooperative-weight MFMA (r7 verbatim) ----------------
__global__ __launch_bounds__(256, 2) void k3_main(const float* __restrict__ adj,
                                                  const unsigned short* __restrict__ ht,
                                                  const float* __restrict__ ssrcL,
                                                  const float* __restrict__ sdstL,
                                                  const float* __restrict__ carr,
                                                  float* __restrict__ out){
  __shared__ __align__(16) unsigned short httile[2][128][64];  // 32 KB (o-rows x j)
  __shared__ __align__(16) unsigned short wtile[2][32][64];    // 8 KB  (i-rows x j)
  const int t    = threadIdx.x;
  const int bxr  = blockIdx.x;
  const int bx   = ((bxr & 7) << 6) | (bxr >> 3);   // batch -> one XCD
  const int b    = bx >> 6;
  const int i0   = (bx & 63) * 32;
  const int w    = t >> 6, lane = t & 63;
  const int r32  = lane & 31, hl = lane >> 5;
  const int r7   = r32 & 7;
  const int wchunk = (w*2 + hl) ^ r7;               // wtile write position
  const long rowg = (long)b*2048 + i0 + r32;
  const float siL = ssrcL[rowg];
  const float Ci  = carr[rowg];
  const float* adjL = adj + rowg*2048 + w*16 + hl*8;      // this lane's weight slice
  const float* sdbL = sdstL + (long)b*2048 + w*16 + hl*8;
  // staging source (this wave's 32 o-rows, source pre-swizzled by j-chunk):
  const unsigned short* sgbase = ht + (long)b*262144
                               + (long)(w*32 + (lane >> 3))*2048
                               + ((lane & 7) ^ (lane >> 3)) * 8;

  f32x16 acc;
#pragma unroll
  for (int e = 0; e < 16; ++e) acc[e] = 0.f;
  f32x4 aA0, aA1, dA0, dA1, aB0, aB1, dB0, dB1;

  // ---- prologue: stage tile0 -> buf0; adj/sd sets for steps 0,1 ----
#pragma unroll
  for (int it = 0; it < 4; ++it)
    __builtin_amdgcn_global_load_lds(
      (const __attribute__((address_space(1))) void*)(sgbase + it*16384),
      (__attribute__((address_space(3))) void*)&httile[0][w*32 + it*8][0], 16, 0, 0);
  aA0 = *(const f32x4*)(adjL);      aA1 = *(const f32x4*)(adjL + 4);
  dA0 = *(const f32x4*)(sdbL);      dA1 = *(const f32x4*)(sdbL + 4);
  aB0 = *(const f32x4*)(adjL + 64); aB1 = *(const f32x4*)(adjL + 68);
  dB0 = *(const f32x4*)(sdbL + 64); dB1 = *(const f32x4*)(sdbL + 68);

#define K3_STEP(JB, BUF, DO_STAGE, DO_REFILL, VMSTR, AV0, AV1, DV0, DV1) do{     \
    if (DO_STAGE){                                                               \
      _Pragma("unroll")                                                          \
      for (int it = 0; it < 4; ++it)                                             \
        __builtin_amdgcn_global_load_lds(                                        \
          (const __attribute__((address_space(1))) void*)(sgbase + (JB) + 64 + it*16384), \
          (__attribute__((address_space(3))) void*)&httile[(BUF)^1][w*32 + it*8][0], 16, 0, 0); \
    }                                                                            \
    {  float wv[8];                                                              \
       _Pragma("unroll")                                                         \
       for (int e = 0; e < 4; ++e){                                              \
         wv[e]   = AV0[e] + fast_exp2(lrelu(siL + DV0[e]) - Ci);                 \
         wv[4+e] = AV1[e] + fast_exp2(lrelu(siL + DV1[e]) - Ci);                 \
       }                                                                         \
       const unsigned p01 = __builtin_amdgcn_perm(__float_as_uint(wv[1]), __float_as_uint(wv[0]), 0x07060302u); \
       const unsigned p23 = __builtin_amdgcn_perm(__float_as_uint(wv[3]), __float_as_uint(wv[2]), 0x07060302u); \
       const unsigned p45 = __builtin_amdgcn_perm(__float_as_uint(wv[5]), __float_as_uint(wv[4]), 0x07060302u); \
       const unsigned p67 = __builtin_amdgcn_perm(__float_as_uint(wv[7]), __float_as_uint(wv[6]), 0x07060302u); \
       int4v ai = {(int)p01, (int)p23, (int)p45, (int)p67};                      \
       *(int4v*)&wtile[BUF][r32][wchunk*8] = ai;                                 \
    }                                                                            \
    if (DO_REFILL){                                                              \
      AV0 = *(const f32x4*)(adjL + (JB) + 128);                                  \
      AV1 = *(const f32x4*)(adjL + (JB) + 132);                                  \
      DV0 = *(const f32x4*)(sdbL + (JB) + 128);                                  \
      DV1 = *(const f32x4*)(sdbL + (JB) + 132);                                  \
    }                                                                            \
    asm volatile("s_waitcnt vmcnt(" VMSTR ") lgkmcnt(0)" ::: "memory");          \
    __builtin_amdgcn_sched_barrier(0);                                           \
    __builtin_amdgcn_s_barrier();                                                \
    __builtin_amdgcn_sched_barrier(0);                                           \
    __builtin_amdgcn_s_setprio(1);                                               \
    _Pragma("unroll")                                                            \
    for (int g = 0; g < 4; ++g){                                                 \
      const int pos = ((2*g + hl) ^ r7) * 8;                                     \
      const bf16x8 afr = *(const bf16x8*)&wtile[BUF][r32][pos];                  \
      const bf16x8 bfr = *(const bf16x8*)&httile[BUF][w*32 + r32][pos];          \
      acc = __builtin_amdgcn_mfma_f32_32x32x16_bf16(afr, bfr, acc, 0, 0, 0);     \
    }                                                                            \
    __builtin_amdgcn_s_setprio(0);                                               \
    __builtin_amdgcn_sched_barrier(0);                                           \
  }while(0)

  for (int kt = 0; kt < 30; kt += 2){
    const int jb0 = kt * 64;
    K3_STEP(jb0,      0, 1, 1, "8", aA0, aA1, dA0, dA1);
    K3_STEP(jb0 + 64, 1, 1, 1, "8", aB0, aB1, dB0, dB1);
  }
  K3_STEP(1920, 0, 1, 0, "8", aA0, aA1, dA0, dA1);  // s=30: stage tile 31
  K3_STEP(1984, 1, 0, 0, "0", aB0, aB1, dB0, dB1);  // s=31: final
#undef K3_STEP

  // ---- epilogue: direct store (full-K acc per wave) ----
#pragma unroll
  for (int rg = 0; rg < 16; ++rg){
    const int rr = (rg & 3) + 8*(rg >> 2) + 4*hl;
    out[((long)b*2048 + i0 + rr)*128 + w*32 + r32] = lrelu(acc[rg]);
  }
}

extern "C" void kernel_launch(void* const* d_in, const int* in_sizes, int n_in,
                              void* d_out, int out_size, void* d_ws, size_t ws_size,
                              hipStream_t stream){
  const float* x   = (const float*)d_in[0];
  const float* adj = (const float*)d_in[1];
  const float* W   = (const float*)d_in[2];
  const float* a   = (const float*)d_in[3];
  float* out = (float*)d_out;
  char* ws = (char*)d_ws;

  unsigned short* ht    = (unsigned short*)(ws);              // 4 MB
  float*          ssrcL = (float*)(ws + 4194304);             // 64 KB
  float*          sdstL = (float*)(ws + 4259840);             // 64 KB
  float*          carr  = (float*)(ws + 4325376);             // 64 KB
  unsigned short* Wt    = (unsigned short*)(ws + 4390912);    // 32 KB
  unsigned*       Mu    = (unsigned*)(ws + 4423680);          // 32 B

  k0_wt   <<<16,   256, 0, stream>>>(W, Wt, Mu);
  k1_fused<<<512,  256, 0, stream>>>(x, Wt, a, ht, ssrcL, sdstL, Mu);
  k2_ml   <<<4096, 256, 0, stream>>>(ssrcL, sdstL, Mu, carr);
  k3_main <<<512,  256, 0, stream>>>(adj, ht, ssrcL, sdstL, carr, out);
}

// Round 14
// 52.999 us; speedup vs baseline: 1.1333x; 1.0829x over previous
//
#include <hip/hip_runtime.h>
#include <hip/hip_bf16.h>

#define NEG 0.2f
#define LOG2E 1.4426950408889634f

typedef __attribute__((ext_vector_type(8))) short bf16x8;
typedef __attribute__((ext_vector_type(4))) float f32x4;
typedef __attribute__((ext_vector_type(16))) float f32x16;
typedef __attribute__((ext_vector_type(4))) int int4v;

__device__ __forceinline__ float lrelu(float t){ return fmaxf(t, NEG * t); }
__device__ __forceinline__ float fast_exp2(float x){
  float r; asm("v_exp_f32 %0, %1" : "=v"(r) : "v"(x)); return r;
}
__device__ __forceinline__ unsigned short f2bf(float f){   // RNE
  union { float f; unsigned int u; } v; v.f = f;
  unsigned int r = v.u + 0x7FFFu + ((v.u >> 16) & 1u);
  return (unsigned short)(r >> 16);
}
// order-preserving float->uint mapping for atomicMax
__device__ __forceinline__ unsigned fmap(float f){
  unsigned u = __float_as_uint(f);
  return (u & 0x80000000u) ? ~u : (u | 0x80000000u);
}
__device__ __forceinline__ float funmap(unsigned u){
  return (u & 0x80000000u) ? __uint_as_float(u & 0x7FFFFFFFu) : __uint_as_float(~u);
}

// ---------------- K0: Wt[o][k] = bf16(W[k][o]), 16 blocks; block 0 zeroes Mu ----------------
__global__ __launch_bounds__(256) void k0_wt(const float* __restrict__ W,
                                             unsigned short* __restrict__ Wt,
                                             unsigned* __restrict__ Mu){
  __shared__ __align__(16) unsigned short wl[8*136];
  const int t = threadIdx.x;
  const int p = blockIdx.x;            // o-slab [p*8, p*8+8)
  if (p == 0 && t < 8) Mu[t] = 0u;
  {
    const int k = t >> 1, h = t & 1;
    f32x4 v = *(const f32x4*)(W + k*128 + p*8 + h*4);
#pragma unroll
    for (int e = 0; e < 4; ++e) wl[(h*4 + e)*136 + k] = f2bf(v[e]);
  }
  __syncthreads();
  {
    const int ol = t >> 5, ks = (t & 31) * 4;
    unsigned int lo = *(const unsigned int*)(wl + ol*136 + ks);
    unsigned int hi = *(const unsigned int*)(wl + ol*136 + ks + 2);
    *(unsigned int*)(Wt + (p*8 + ol)*128 + ks)     = lo;
    *(unsigned int*)(Wt + (p*8 + ol)*128 + ks + 2) = hi;
  }
}

// ---------------- K1: h^T via MFMA + scaled s_src/s_dst (+batch-max atomic) + ht store ----------------
__global__ __launch_bounds__(256) void k1_fused(const float* __restrict__ x,
                                                const unsigned short* __restrict__ Wt,
                                                const float* __restrict__ a,
                                                unsigned short* __restrict__ ht,
                                                float* __restrict__ ssrcL,
                                                float* __restrict__ sdstL,
                                                unsigned* __restrict__ Mu){
  __shared__ __align__(16) unsigned short wtl[128*136];
  __shared__ __align__(16) unsigned short xl[32*136];
  __shared__ __align__(16) unsigned short tlw[128*34];
  __shared__ float sred[2][4][2][16];
  const int t = threadIdx.x;
  const int bx = blockIdx.x;                 // b*64 + jt
  const int b  = bx >> 6;
  const int jt = bx & 63;
  const long rowbase = (long)bx * 32;
  {
    const int o = t >> 1, seg = (t & 1) * 64;
    const int4v* src = (const int4v*)(Wt + o*128 + seg);
    int4v* dst = (int4v*)(wtl + o*136 + seg);
#pragma unroll
    for (int g = 0; g < 8; ++g) dst[g] = src[g];
  }
  {
    const int i = t >> 3, ks = (t & 7) * 16;
    const f32x4* src = (const f32x4*)(x + (rowbase + i)*128 + ks);
    unsigned int q[8];
#pragma unroll
    for (int g = 0; g < 4; ++g){
      f32x4 v = src[g];
      q[g*2]   = (unsigned)f2bf(v[0]) | ((unsigned)f2bf(v[1]) << 16);
      q[g*2+1] = (unsigned)f2bf(v[2]) | ((unsigned)f2bf(v[3]) << 16);
    }
    int4v* dst = (int4v*)(xl + i*136 + ks);
    dst[0] = *(int4v*)&q[0];
    dst[1] = *(int4v*)&q[4];
  }
  __syncthreads();
  const int w = t >> 6, lane = t & 63, lr = lane & 15, hi = lane >> 4;
  f32x4 zro = {0.f, 0.f, 0.f, 0.f};
  f32x4 acc00 = zro, acc01 = zro, acc10 = zro, acc11 = zro;
#pragma unroll
  for (int ks = 0; ks < 4; ++ks){
    const bf16x8 a0 = *(const bf16x8*)(wtl + (w*32      + lr)*136 + ks*32 + hi*8);
    const bf16x8 a1 = *(const bf16x8*)(wtl + (w*32 + 16 + lr)*136 + ks*32 + hi*8);
    const bf16x8 b0 = *(const bf16x8*)(xl + (     lr)*136 + ks*32 + hi*8);
    const bf16x8 b1 = *(const bf16x8*)(xl + (16 + lr)*136 + ks*32 + hi*8);
    acc00 = __builtin_amdgcn_mfma_f32_16x16x32_bf16(a0, b0, acc00, 0, 0, 0);
    acc01 = __builtin_amdgcn_mfma_f32_16x16x32_bf16(a0, b1, acc01, 0, 0, 0);
    acc10 = __builtin_amdgcn_mfma_f32_16x16x32_bf16(a1, b0, acc10, 0, 0, 0);
    acc11 = __builtin_amdgcn_mfma_f32_16x16x32_bf16(a1, b1, acc11, 0, 0, 0);
  }
  {
    const f32x4 as0 = *(const f32x4*)(a +       w*32      + hi*4);
    const f32x4 as1 = *(const f32x4*)(a +       w*32 + 16 + hi*4);
    const f32x4 ad0 = *(const f32x4*)(a + 128 + w*32      + hi*4);
    const f32x4 ad1 = *(const f32x4*)(a + 128 + w*32 + 16 + hi*4);
    float ps0, ps1, pd0, pd1;
    {
      f32x4 u = acc00*as0 + acc10*as1;  ps0 = u[0]+u[1]+u[2]+u[3];
      f32x4 v = acc01*as0 + acc11*as1;  ps1 = v[0]+v[1]+v[2]+v[3];
      f32x4 p = acc00*ad0 + acc10*ad1;  pd0 = p[0]+p[1]+p[2]+p[3];
      f32x4 r = acc01*ad0 + acc11*ad1;  pd1 = r[0]+r[1]+r[2]+r[3];
    }
#pragma unroll
    for (int off = 16; off <= 32; off <<= 1){
      ps0 += __shfl_xor(ps0, off); ps1 += __shfl_xor(ps1, off);
      pd0 += __shfl_xor(pd0, off); pd1 += __shfl_xor(pd1, off);
    }
    if (hi == 0){
      sred[0][w][0][lr] = ps0; sred[0][w][1][lr] = ps1;
      sred[1][w][0][lr] = pd0; sred[1][w][1][lr] = pd1;
    }
  }
#pragma unroll
  for (int q = 0; q < 4; ++q){
    tlw[(w*32      + hi*4 + q)*34      + lr] = f2bf(acc00[q]);
    tlw[(w*32      + hi*4 + q)*34 + 16 + lr] = f2bf(acc01[q]);
    tlw[(w*32 + 16 + hi*4 + q)*34      + lr] = f2bf(acc10[q]);
    tlw[(w*32 + 16 + hi*4 + q)*34 + 16 + lr] = f2bf(acc11[q]);
  }
  __syncthreads();
  {
    const int o = t >> 1, jseg = (t & 1) * 16;
    const unsigned int* src = (const unsigned int*)(tlw + o*34 + jseg);
    unsigned int p[8];
#pragma unroll
    for (int g = 0; g < 8; ++g) p[g] = src[g];
    unsigned short* dst = ht + (long)b*262144 + (long)o*2048 + jt*32 + jseg;
    ((int4v*)dst)[0] = *(int4v*)&p[0];
    ((int4v*)dst)[1] = *(int4v*)&p[4];
  }
  if (t < 64){
    const int sel = t >> 5, jl = t & 31;
    const int ig = jl >> 4, l2 = jl & 15;
    const float s = (sred[sel][0][ig][l2] + sred[sel][1][ig][l2]
                   + sred[sel][2][ig][l2] + sred[sel][3][ig][l2]) * LOG2E;
    if (sel == 0){
      ssrcL[rowbase + jl] = s;
    } else {
      sdstL[rowbase + jl] = s;
      unsigned u = fmap(s);
#pragma unroll
      for (int off = 1; off <= 16; off <<= 1){
        unsigned o2 = (unsigned)__shfl_xor((int)u, off);
        u = u > o2 ? u : o2;
      }
      if (jl == 0) atomicMax(&Mu[b], u);
    }
  }
}

// ---------------- K3: out = LR( adj@h + (1/l)·(Pu@h) ), dual-accumulator, k2 fused away ----------------
// grid 512 = 8b x 64 tiles (BM=32, XCD-swizzled); block 256 = 4 waves (r7 schedule).
// Pu_ij = 2^(lrelu(siL+sjL) - mL_i), mL_i = lrelu(siL + Mb) = exact row max (lrelu monotone).
// Each step: stage ht (global_load_lds, pre-swizzled src), compute adj-bf16 AND Pu-bf16
// cooperative tiles, 8 MFMA (4 k-subs x {adj,Pu}); lane accumulates lsum over its j-slice.
// Epilogue: 8-way LDS reduce of lsum -> l_i; out = lrelu(acc_a + acc_p / l_i).
__global__ __launch_bounds__(256, 2) void k3_main(const float* __restrict__ adj,
                                                  const unsigned short* __restrict__ ht,
                                                  const float* __restrict__ ssrcL,
                                                  const float* __restrict__ sdstL,
                                                  const unsigned* __restrict__ Mu,
                                                  float* __restrict__ out){
  __shared__ __align__(16) unsigned short httile[2][128][64];  // 32 KB
  __shared__ __align__(16) unsigned short atile[2][32][64];    // 8 KB adj bf16
  __shared__ __align__(16) unsigned short ptile[2][32][64];    // 8 KB Pu bf16
  __shared__ float lred[32][8];
  __shared__ float linv[32];
  const int t    = threadIdx.x;
  const int bxr  = blockIdx.x;
  const int bx   = ((bxr & 7) << 6) | (bxr >> 3);   // batch -> one XCD
  const int b    = bx >> 6;
  const int i0   = (bx & 63) * 32;
  const int w    = t >> 6, lane = t & 63;
  const int r32  = lane & 31, hl = lane >> 5;
  const int r7   = r32 & 7;
  const int wchunk = (w*2 + hl) ^ r7;
  const long rowg = (long)b*2048 + i0 + r32;
  const float siL = ssrcL[rowg];
  const float mL  = lrelu(siL + funmap(Mu[b]));     // exact row max of lrelu(siL+sjL)
  const float* adjL = adj + rowg*2048 + w*16 + hl*8;
  const float* sdbL = sdstL + (long)b*2048 + w*16 + hl*8;
  const unsigned short* sgbase = ht + (long)b*262144
                               + (long)(w*32 + (lane >> 3))*2048
                               + ((lane & 7) ^ (lane >> 3)) * 8;

  f32x16 acc_a, acc_p;
#pragma unroll
  for (int e = 0; e < 16; ++e){ acc_a[e] = 0.f; acc_p[e] = 0.f; }
  float lsum = 0.f;
  f32x4 aA0, aA1, dA0, dA1, aB0, aB1, dB0, dB1;

  // ---- prologue: stage tile0 -> buf0; adj/sd sets for steps 0,1 ----
#pragma unroll
  for (int it = 0; it < 4; ++it)
    __builtin_amdgcn_global_load_lds(
      (const __attribute__((address_space(1))) void*)(sgbase + it*16384),
      (__attribute__((address_space(3))) void*)&httile[0][w*32 + it*8][0], 16, 0, 0);
  aA0 = *(const f32x4*)(adjL);      aA1 = *(const f32x4*)(adjL + 4);
  dA0 = *(const f32x4*)(sdbL);      dA1 = *(const f32x4*)(sdbL + 4);
  aB0 = *(const f32x4*)(adjL + 64); aB1 = *(const f32x4*)(adjL + 68);
  dB0 = *(const f32x4*)(sdbL + 64); dB1 = *(const f32x4*)(sdbL + 68);

#define K3_STEP(JB, BUF, DO_STAGE, DO_REFILL, VMSTR, AV0, AV1, DV0, DV1) do{     \
    if (DO_STAGE){                                                               \
      _Pragma("unroll")                                                          \
      for (int it = 0; it < 4; ++it)                                             \
        __builtin_amdgcn_global_load_lds(                                        \
          (const __attribute__((address_space(1))) void*)(sgbase + (JB) + 64 + it*16384), \
          (__attribute__((address_space(3))) void*)&httile[(BUF)^1][w*32 + it*8][0], 16, 0, 0); \
    }                                                                            \
    {  float pv[8];                                                              \
       _Pragma("unroll")                                                         \
       for (int e = 0; e < 4; ++e){                                              \
         pv[e]   = fast_exp2(lrelu(siL + DV0[e]) - mL);                          \
         pv[4+e] = fast_exp2(lrelu(siL + DV1[e]) - mL);                          \
       }                                                                         \
       lsum += ((pv[0]+pv[1])+(pv[2]+pv[3])) + ((pv[4]+pv[5])+(pv[6]+pv[7]));    \
       const unsigned q01 = __builtin_amdgcn_perm(__float_as_uint(pv[1]), __float_as_uint(pv[0]), 0x07060302u); \
       const unsigned q23 = __builtin_amdgcn_perm(__float_as_uint(pv[3]), __float_as_uint(pv[2]), 0x07060302u); \
       const unsigned q45 = __builtin_amdgcn_perm(__float_as_uint(pv[5]), __float_as_uint(pv[4]), 0x07060302u); \
       const unsigned q67 = __builtin_amdgcn_perm(__float_as_uint(pv[7]), __float_as_uint(pv[6]), 0x07060302u); \
       int4v pi = {(int)q01, (int)q23, (int)q45, (int)q67};                      \
       *(int4v*)&ptile[BUF][r32][wchunk*8] = pi;                                 \
       const unsigned a01 = __builtin_amdgcn_perm(__float_as_uint(AV0[1]), __float_as_uint(AV0[0]), 0x07060302u); \
       const unsigned a23 = __builtin_amdgcn_perm(__float_as_uint(AV0[3]), __float_as_uint(AV0[2]), 0x07060302u); \
       const unsigned a45 = __builtin_amdgcn_perm(__float_as_uint(AV1[1]), __float_as_uint(AV1[0]), 0x07060302u); \
       const unsigned a67 = __builtin_amdgcn_perm(__float_as_uint(AV1[3]), __float_as_uint(AV1[2]), 0x07060302u); \
       int4v ai = {(int)a01, (int)a23, (int)a45, (int)a67};                      \
       *(int4v*)&atile[BUF][r32][wchunk*8] = ai;                                 \
    }                                                                            \
    if (DO_REFILL){                                                              \
      AV0 = *(const f32x4*)(adjL + (JB) + 128);                                  \
      AV1 = *(const f32x4*)(adjL + (JB) + 132);                                  \
      DV0 = *(const f32x4*)(sdbL + (JB) + 128);                                  \
      DV1 = *(const f32x4*)(sdbL + (JB) + 132);                                  \
    }                                                                            \
    asm volatile("s_waitcnt vmcnt(" VMSTR ") lgkmcnt(0)" ::: "memory");          \
    __builtin_amdgcn_sched_barrier(0);                                           \
    __builtin_amdgcn_s_barrier();                                                \
    __builtin_amdgcn_sched_barrier(0);                                           \
    __builtin_amdgcn_s_setprio(1);                                               \
    _Pragma("unroll")                                                            \
    for (int g = 0; g < 4; ++g){                                                 \
      const int pos = ((2*g + hl) ^ r7) * 8;                                     \
      const bf16x8 bfr = *(const bf16x8*)&httile[BUF][w*32 + r32][pos];          \
      const bf16x8 afr = *(const bf16x8*)&atile[BUF][r32][pos];                  \
      const bf16x8 pfr = *(const bf16x8*)&ptile[BUF][r32][pos];                  \
      acc_a = __builtin_amdgcn_mfma_f32_32x32x16_bf16(afr, bfr, acc_a, 0, 0, 0); \
      acc_p = __builtin_amdgcn_mfma_f32_32x32x16_bf16(pfr, bfr, acc_p, 0, 0, 0); \
    }                                                                            \
    __builtin_amdgcn_s_setprio(0);                                               \
    __builtin_amdgcn_sched_barrier(0);                                           \
  }while(0)

  for (int kt = 0; kt < 30; kt += 2){
    const int jb0 = kt * 64;
    K3_STEP(jb0,      0, 1, 1, "8", aA0, aA1, dA0, dA1);
    K3_STEP(jb0 + 64, 1, 1, 1, "8", aB0, aB1, dB0, dB1);
  }
  K3_STEP(1920, 0, 1, 0, "8", aA0, aA1, dA0, dA1);  // s=30: stage tile 31
  K3_STEP(1984, 1, 0, 0, "0", aB0, aB1, dB0, dB1);  // s=31: final
#undef K3_STEP

  // ---- epilogue: reduce l_i (8 slices per row), combine, store ----
  lred[r32][w*2 + hl] = lsum;
  __syncthreads();
  if (t < 32){
    const float* lr = &lred[t][0];
    const float l = ((lr[0]+lr[1]) + (lr[2]+lr[3])) + ((lr[4]+lr[5]) + (lr[6]+lr[7]));
    linv[t] = 1.f / l;
  }
  __syncthreads();
#pragma unroll
  for (int rg = 0; rg < 16; ++rg){
    const int rr = (rg & 3) + 8*(rg >> 2) + 4*hl;
    const float v = acc_a[rg] + acc_p[rg] * linv[rr];
    out[((long)b*2048 + i0 + rr)*128 + w*32 + r32] = lrelu(v);
  }
}

extern "C" void kernel_launch(void* const* d_in, const int* in_sizes, int n_in,
                              void* d_out, int out_size, void* d_ws, size_t ws_size,
                              hipStream_t stream){
  const float* x   = (const float*)d_in[0];
  const float* adj = (const float*)d_in[1];
  const float* W   = (const float*)d_in[2];
  const float* a   = (const float*)d_in[3];
  float* out = (float*)d_out;
  char* ws = (char*)d_ws;

  unsigned short* ht    = (unsigned short*)(ws);              // 4 MB
  float*          ssrcL = (float*)(ws + 4194304);             // 64 KB
  float*          sdstL = (float*)(ws + 4259840);             // 64 KB
  unsigned short* Wt    = (unsigned short*)(ws + 4325376);    // 32 KB
  unsigned*       Mu    = (unsigned*)(ws + 4358144);          // 32 B

  k0_wt   <<<16,  256, 0, stream>>>(W, Wt, Mu);
  k1_fused<<<512, 256, 0, stream>>>(x, Wt, a, ht, ssrcL, sdstL, Mu);
  k3_main <<<512, 256, 0, stream>>>(adj, ht, ssrcL, sdstL, Mu, out);
}